// Round 5
// baseline (501.705 us; speedup 1.0000x reference)
//
#include <hip/hip_runtime.h>
#include <hip/hip_cooperative_groups.h>
#include <math.h>

namespace cg = cooperative_groups;

// Problem constants: N=50000, E=800000, D=H=64, ED=16.
// Pipeline v6: cooperative fused kernel (grid-strided phases, occupancy-
// sized grid, error-checked launch) with PROVEN split pipeline as fallback.
//   ph1 bin+pack: bucket=dst>>7 (391 buckets x 128 nodes). Per 2048-edge
//        chunk: LDS histogram -> local rank; ONE global atomic per
//        (bucket,chunk); edges packed (dloc<<16|src) into region.
//   ph2 build_csr: bucket per block, CSR in LDS, cnt+csr_pad streamed out.
//   ph3 node_gemm: gbf = bf16(rsqrt(cnt+1)*(x@W1)).
//   ph4 gather:    hbf = bf16(relu(rsqrt(cnt+1)*(gbf[i]+sum gbf[s])+b1)).
//   ph5 edge_mlp:  out = sigmoid(relu([h_s|h_d|ea]@Wm1+bm1)@Wm2+bm2).
//
// R4 LESSON: unchecked hipLaunchCooperativeKernel(GRID=1280) silently
// failed (absmax 0.765 == all-zero output; 468 == poison retained ->
// kernel never ran; no hang -> launch rejected, not deadlock). Fixes:
//  (a) grid-stride ALL phases -> correct at any grid size;
//  (b) size grid via hipOccupancyMaxActiveBlocksPerMultiprocessor x CUs
//      (cached static; queries are capture-safe);
//  (c) check launch rc; fallback = R3-proven split pipeline (194us).
//  (d) ph2 trailing __syncthreads (lcnt re-zero race when grid < NBUCK);
//  (e) region aliased onto hbf (dead before ph4) -> ws 23.5 -> 19.5 MB.
//
// LESSONS ENCODED:
//  - hbf must NOT alias gbf (cross-block RW race).
//  - edge_mlp pinned ~48.5us across 6 variants: random-row fetch bound.
//  - R2: random-scatter cost is per-EVENT (~55B/edge) -> keep stores binned.
//  - R3: kernel-work sum (~100us) << total (194us): ~16us/dispatch gap ->
//    fusion is the lever, not per-kernel tuning.
//  - cnt holds TRUE degree (count unconditional, store guarded at 64);
//    max indeg ~45 (seed 0); CAP=2560 = mean 2046 + 11 sigma.

typedef __attribute__((ext_vector_type(8))) short bf16x8;
typedef __attribute__((ext_vector_type(4))) float f32x4;

#define MAXDEG 64
#define BSHIFT 7           // 128 nodes per bucket
#define BMASK 127
#define NBUCK 391          // ceil(50000/128)
#define CAP 2560           // per-bucket region capacity (mean 2046 + 11s)
#define CHUNK 2048         // edges per ph1 chunk
#define NCHUNK 391         // ceil(800000/2048)
#define PACKB 56           // weight-pack virtual blocks

__device__ __forceinline__ unsigned short f2b(float f) {
    unsigned u = __float_as_uint(f);
    unsigned r = (u + 0x7FFFu + ((u >> 16) & 1u)) >> 16;   // RNE
    return (unsigned short)r;
}

// ============================ fused cooperative =============================
__global__ void __launch_bounds__(256, 5) fused_gcn(
        const float* __restrict__ x, const int* __restrict__ src,
        const int* __restrict__ dst, const float* __restrict__ ea,
        const float* __restrict__ W1, const float* __restrict__ b1,
        const float* __restrict__ Wm1, const float* __restrict__ bm1,
        const float* __restrict__ Wm2, const float* __restrict__ bm2,
        float* __restrict__ out,
        unsigned short* __restrict__ gbf, unsigned short* __restrict__ hbf,
        unsigned short* __restrict__ csr_pad, unsigned int* __restrict__ region,
        int* __restrict__ cnt, int* __restrict__ gcur,
        unsigned short* __restrict__ Bp, unsigned short* __restrict__ Bp1,
        int N, int E) {
    cg::grid_group grid = cg::this_grid();
    __shared__ char smem[20480];   // union: ph1 3.1K | ph2 16.9K | ph3 8K | ph5 20K
    const int tid = threadIdx.x;
    const int bid = blockIdx.x;
    const int gdim = gridDim.x;
    const int wave = tid >> 6, lane = tid & 63;

    // ===== ph1: bin edges into dst-buckets (+ weight pack), grid-stride =====
    for (int vb = bid; vb < NCHUNK + PACKB; vb += gdim) {
        if (vb < NCHUNK) {
            int* lc = (int*)smem;
            int* gb = lc + NBUCK;
            for (int i = tid; i < NBUCK; i += 256) lc[i] = 0;
            __syncthreads();
            int base = vb * CHUNK + tid * 8;   // 8 consecutive edges/thread
            unsigned key[8], val[8];
#pragma unroll
            for (int k = 0; k < 8; ++k) {
                int e = base + k;
                key[k] = 0xFFFFFFFFu;
                if (e < E) {
                    int d = dst[e], s = src[e];
                    int b = d >> BSHIFT;
                    int r = atomicAdd(&lc[b], 1);        // LDS atomic: local rank
                    key[k] = (unsigned)b | ((unsigned)r << 9);   // b<512, r<2048
                    val[k] = ((unsigned)(d & BMASK) << 16) | (unsigned)s;
                }
            }
            __syncthreads();
            for (int i = tid; i < NBUCK; i += 256) {
                int t = lc[i];
                gb[i] = t ? atomicAdd(&gcur[i], t) : 0;  // ONE global atomic/bucket
            }
            __syncthreads();
#pragma unroll
            for (int k = 0; k < 8; ++k) {
                if (key[k] != 0xFFFFFFFFu) {
                    int b = (int)(key[k] & 511u), r = (int)(key[k] >> 9);
                    int idx = gb[b] + r;
                    if (idx < CAP) region[(size_t)b * CAP + idx] = val[k];
                }
            }
        } else {
            // pack Wm1 [144x64]->Bp (5 K-steps, K padded 160), W1 [64x64]->Bp1
            // in mfma_f32_16x16x32_bf16 B-frag layout.
            int idx = (vb - NCHUNK) * 256 + tid;
            if (idx < 10240) {
                int j = idx & 7, ln = (idx >> 3) & 63, t = (idx >> 9) & 3, s = idx >> 11;
                int k = s * 32 + (ln >> 4) * 8 + j, col = t * 16 + (ln & 15);
                float v = (k < 144) ? Wm1[k * 64 + col] : 0.0f;
                Bp[idx] = f2b(v);
            } else {
                int idx2 = idx - 10240;
                if (idx2 < 4096) {
                    int j = idx2 & 7, ln = (idx2 >> 3) & 63, t = (idx2 >> 9) & 3, s = idx2 >> 11;
                    int k = s * 32 + (ln >> 4) * 8 + j, col = t * 16 + (ln & 15);
                    Bp1[idx2] = f2b(W1[k * 64 + col]);
                }
            }
        }
        __syncthreads();   // protect smem reuse across strided iterations
    }
    grid.sync();

    // ===== ph2: build padded CSR per bucket (128 nodes), grid-stride =====
    for (int vb = bid; vb < NBUCK; vb += gdim) {
        unsigned short* lcsr = (unsigned short*)smem;          // 16 KB
        int* lcnt = (int*)(smem + 16384);                      // 512 B
        if (tid < 128) lcnt[tid] = 0;
        __syncthreads();
        int ecnt = gcur[vb]; if (ecnt > CAP) ecnt = CAP;
        const unsigned int* reg = region + (size_t)vb * CAP;
        for (int i = tid; i < ecnt; i += 256) {
            unsigned v = reg[i];
            int dloc = (int)(v >> 16), s = (int)(v & 0xFFFFu);
            int r = atomicAdd(&lcnt[dloc], 1);                 // true degree
            if (r < MAXDEG) lcsr[dloc * MAXDEG + r] = (unsigned short)s;
        }
        __syncthreads();
        int n0 = vb << BSHIFT;
        int nb = N - n0; if (nb > 128) nb = 128;
        if (tid < nb) cnt[n0 + tid] = lcnt[tid];
        int4* gout = (int4*)(csr_pad + (size_t)n0 * MAXDEG);
        const int4* lin = (const int4*)lcsr;
        int tot = nb * 8;   // nb rows x 64 ushorts
        for (int i = tid; i < tot; i += 256) gout[i] = lin[i];
        __syncthreads();   // R4 fix: lcnt/lcsr re-zero race for next iteration
    }
    grid.sync();

    // ===== ph3: node GEMM (wave per 16 rows, grid-stride) =====
    {
        unsigned short* sB1 = (unsigned short*)smem;   // 8 KB
        const int4* gB = (const int4*)Bp1;
        int4* lB = (int4*)sB1;
#pragma unroll
        for (int i = 0; i < 2; ++i)
            lB[tid + i * 256] = gB[tid + i * 256];
        __syncthreads();
        int m = lane & 15, quad = lane >> 4;
        int NWT = N / 16;   // 3125
        const bf16x8* bp = (const bf16x8*)sB1;
        for (int wid = bid * 4 + wave; wid < NWT; wid += gdim * 4) {
            int r0 = wid * 16;
            f32x4 acc[4];
#pragma unroll
            for (int t = 0; t < 4; ++t) acc[t] = (f32x4){0.f, 0.f, 0.f, 0.f};
#pragma unroll
            for (int s = 0; s < 2; ++s) {
                const float4* xp = (const float4*)(x + (size_t)(r0 + m) * 64 + s * 32 + quad * 8);
                float4 v0 = xp[0], v1 = xp[1];
                bf16x8 a;
                a[0] = (short)f2b(v0.x); a[1] = (short)f2b(v0.y);
                a[2] = (short)f2b(v0.z); a[3] = (short)f2b(v0.w);
                a[4] = (short)f2b(v1.x); a[5] = (short)f2b(v1.y);
                a[6] = (short)f2b(v1.z); a[7] = (short)f2b(v1.w);
#pragma unroll
                for (int t = 0; t < 4; ++t)
                    acc[t] = __builtin_amdgcn_mfma_f32_16x16x32_bf16(
                        a, bp[(s * 4 + t) * 64 + lane], acc[t], 0, 0, 0);
            }
#pragma unroll
            for (int reg = 0; reg < 4; ++reg) {
                int row = r0 + quad * 4 + reg;
                float di = rsqrtf((float)cnt[row] + 1.0f);
#pragma unroll
                for (int t = 0; t < 4; ++t)
                    gbf[(size_t)row * 64 + t * 16 + m] = f2b(acc[t][reg] * di);
            }
        }
    }
    grid.sync();

    // ===== ph4: gather + finalize (wave per node, grid-stride) =====
    {
        int n8 = lane >> 3, c8 = lane & 7;
        const int4* gb4 = (const int4*)gbf;   // row stride = 8 int4 (128 B)
        for (int wid = bid * 4 + wave; wid < N; wid += gdim * 4) {
            int deg = cnt[wid];
            if (deg > MAXDEG) deg = MAXDEG;   // never hit: max indeg ~45
            size_t base = (size_t)wid << 6;
            float a[8];
#pragma unroll
            for (int k = 0; k < 8; ++k) a[k] = 0.f;
            for (int j0 = 0; j0 < deg; j0 += 64) {
                int nidx = j0 + lane;
                int sidx = (nidx < deg) ? (int)csr_pad[base + nidx] : 0;
                int c = deg - j0; if (c > 64) c = 64;
                for (int step = 0; step * 8 < c; ++step) {
                    int nn = step * 8 + n8;
                    int srow = __shfl(sidx, nn, 64);
                    int4 u = make_int4(0, 0, 0, 0);
                    if (nn < c) u = gb4[(size_t)srow * 8 + c8];
                    a[0] += __uint_as_float((unsigned)u.x << 16);
                    a[1] += __uint_as_float((unsigned)u.x & 0xffff0000u);
                    a[2] += __uint_as_float((unsigned)u.y << 16);
                    a[3] += __uint_as_float((unsigned)u.y & 0xffff0000u);
                    a[4] += __uint_as_float((unsigned)u.z << 16);
                    a[5] += __uint_as_float((unsigned)u.z & 0xffff0000u);
                    a[6] += __uint_as_float((unsigned)u.w << 16);
                    a[7] += __uint_as_float((unsigned)u.w & 0xffff0000u);
                }
            }
#pragma unroll
            for (int mask = 8; mask < 64; mask <<= 1) {
#pragma unroll
                for (int k = 0; k < 8; ++k) a[k] += __shfl_xor(a[k], mask, 64);
            }
            {   // self loop (add ONCE, after reduction)
                int4 u = gb4[(size_t)wid * 8 + c8];
                a[0] += __uint_as_float((unsigned)u.x << 16);
                a[1] += __uint_as_float((unsigned)u.x & 0xffff0000u);
                a[2] += __uint_as_float((unsigned)u.y << 16);
                a[3] += __uint_as_float((unsigned)u.y & 0xffff0000u);
                a[4] += __uint_as_float((unsigned)u.z << 16);
                a[5] += __uint_as_float((unsigned)u.z & 0xffff0000u);
                a[6] += __uint_as_float((unsigned)u.w << 16);
                a[7] += __uint_as_float((unsigned)u.w & 0xffff0000u);
            }
            if (n8 == 0) {
                float di = rsqrtf((float)deg + 1.0f);
                const float4* bv = (const float4*)(b1 + c8 * 8);
                float4 b0 = bv[0], b14 = bv[1];
                float h0 = di * a[0] + b0.x,  h1 = di * a[1] + b0.y;
                float h2 = di * a[2] + b0.z,  h3 = di * a[3] + b0.w;
                float h4 = di * a[4] + b14.x, h5 = di * a[5] + b14.y;
                float h6 = di * a[6] + b14.z, h7 = di * a[7] + b14.w;
                h0 = h0 > 0.f ? h0 : 0.f; h1 = h1 > 0.f ? h1 : 0.f;
                h2 = h2 > 0.f ? h2 : 0.f; h3 = h3 > 0.f ? h3 : 0.f;
                h4 = h4 > 0.f ? h4 : 0.f; h5 = h5 > 0.f ? h5 : 0.f;
                h6 = h6 > 0.f ? h6 : 0.f; h7 = h7 > 0.f ? h7 : 0.f;
                int4 w;
                w.x = (int)((unsigned)f2b(h0) | ((unsigned)f2b(h1) << 16));
                w.y = (int)((unsigned)f2b(h2) | ((unsigned)f2b(h3) << 16));
                w.z = (int)((unsigned)f2b(h4) | ((unsigned)f2b(h5) << 16));
                w.w = (int)((unsigned)f2b(h6) | ((unsigned)f2b(h7) << 16));
                ((int4*)hbf)[(size_t)wid * 8 + c8] = w;
            }
        }
    }
    grid.sync();

    // ===== ph5: edge MLP (wave per 16 edges, grid-stride) =====
    {
        unsigned short* sB = (unsigned short*)smem;   // 20 KB
        const int4* gB = (const int4*)Bp;
        int4* lB = (int4*)sB;
#pragma unroll
        for (int i = 0; i < 5; ++i)
            lB[tid + i * 256] = gB[tid + i * 256];
        __syncthreads();
        int m = lane & 15, quad = lane >> 4;
        const bf16x8* bp = (const bf16x8*)sB;
        int NG = E >> 4;   // 50000 (E = 800000 = 50000*16 exactly)
        float b2 = bm2[0];
        float w2[4], bb[4];
#pragma unroll
        for (int t = 0; t < 4; ++t) {
            int col = t * 16 + m;
            bb[t] = bm1[col];
            w2[t] = Wm2[col];
        }
        for (int g = bid * 4 + wave; g < NG; g += gdim * 4) {
            int e0 = g * 16;
            int e = e0 + m;
            int ec = e < E ? e : E - 1;
            int si = src[ec], di = dst[ec];
            bf16x8 af[5];
            af[0] = *(const bf16x8*)(hbf + (size_t)si * 64 + quad * 8);
            af[1] = *(const bf16x8*)(hbf + (size_t)si * 64 + 32 + quad * 8);
            af[2] = *(const bf16x8*)(hbf + (size_t)di * 64 + quad * 8);
            af[3] = *(const bf16x8*)(hbf + (size_t)di * 64 + 32 + quad * 8);
            if (quad < 2) {
                const float4* ep = (const float4*)(ea + (size_t)ec * 16 + quad * 8);
                float4 v0 = ep[0], v1 = ep[1];
                af[4][0] = (short)f2b(v0.x); af[4][1] = (short)f2b(v0.y);
                af[4][2] = (short)f2b(v0.z); af[4][3] = (short)f2b(v0.w);
                af[4][4] = (short)f2b(v1.x); af[4][5] = (short)f2b(v1.y);
                af[4][6] = (short)f2b(v1.z); af[4][7] = (short)f2b(v1.w);
            } else {
#pragma unroll
                for (int j = 0; j < 8; ++j) af[4][j] = 0;
            }
            __builtin_amdgcn_sched_barrier(0);
            f32x4 acc[4];
#pragma unroll
            for (int t = 0; t < 4; ++t) acc[t] = (f32x4){0.f, 0.f, 0.f, 0.f};
#pragma unroll
            for (int s = 0; s < 5; ++s) {
#pragma unroll
                for (int t = 0; t < 4; ++t)
                    acc[t] = __builtin_amdgcn_mfma_f32_16x16x32_bf16(
                        af[s], bp[(s * 4 + t) * 64 + lane], acc[t], 0, 0, 0);
            }
            float pr[4];
#pragma unroll
            for (int r = 0; r < 4; ++r) {
                float sum = 0.0f;
#pragma unroll
                for (int t = 0; t < 4; ++t) {
                    float hv = acc[t][r] + bb[t];
                    sum += (hv > 0.0f ? hv : 0.0f) * w2[t];
                }
                pr[r] = sum;
            }
#pragma unroll
            for (int off = 1; off < 16; off <<= 1) {
#pragma unroll
                for (int r = 0; r < 4; ++r) pr[r] += __shfl_xor(pr[r], off, 64);
            }
            if (m < 4) {
                int eo = e0 + quad * 4 + m;
                if (eo < E) out[eo] = 1.0f / (1.0f + __expf(-(pr[m] + b2)));
            }
        }
    }
}

// ======================= split fallback (R3-proven) ========================
__global__ void __launch_bounds__(256) bin_pack(
        const int* __restrict__ dst, const int* __restrict__ src,
        unsigned int* __restrict__ region, int* __restrict__ gcur,
        int E, int NB1,
        const float* __restrict__ Wm1, const float* __restrict__ W1,
        unsigned short* __restrict__ Bp, unsigned short* __restrict__ Bp1) {
    if ((int)blockIdx.x >= NB1) {
        int idx = (blockIdx.x - NB1) * 256 + threadIdx.x;
        if (idx < 10240) {
            int j = idx & 7, ln = (idx >> 3) & 63, t = (idx >> 9) & 3, s = idx >> 11;
            int k = s * 32 + (ln >> 4) * 8 + j, col = t * 16 + (ln & 15);
            float v = (k < 144) ? Wm1[k * 64 + col] : 0.0f;
            Bp[idx] = f2b(v);
        } else {
            int idx2 = idx - 10240;
            if (idx2 < 4096) {
                int j = idx2 & 7, ln = (idx2 >> 3) & 63, t = (idx2 >> 9) & 3, s = idx2 >> 11;
                int k = s * 32 + (ln >> 4) * 8 + j, col = t * 16 + (ln & 15);
                Bp1[idx2] = f2b(W1[k * 64 + col]);
            }
        }
        return;
    }
    __shared__ int lc[NBUCK];
    __shared__ int gb[NBUCK];
    int tid = threadIdx.x;
    for (int i = tid; i < NBUCK; i += 256) lc[i] = 0;
    __syncthreads();
    int base = blockIdx.x * CHUNK + tid * 8;
    unsigned key[8], val[8];
#pragma unroll
    for (int k = 0; k < 8; ++k) {
        int e = base + k;
        key[k] = 0xFFFFFFFFu;
        if (e < E) {
            int d = dst[e], s = src[e];
            int b = d >> BSHIFT;
            int r = atomicAdd(&lc[b], 1);
            key[k] = (unsigned)b | ((unsigned)r << 9);
            val[k] = ((unsigned)(d & BMASK) << 16) | (unsigned)s;
        }
    }
    __syncthreads();
    for (int i = tid; i < NBUCK; i += 256) {
        int t = lc[i];
        gb[i] = t ? atomicAdd(&gcur[i], t) : 0;
    }
    __syncthreads();
#pragma unroll
    for (int k = 0; k < 8; ++k) {
        if (key[k] != 0xFFFFFFFFu) {
            int b = (int)(key[k] & 511u), r = (int)(key[k] >> 9);
            int idx = gb[b] + r;
            if (idx < CAP) region[(size_t)b * CAP + idx] = val[k];
        }
    }
}

__global__ void __launch_bounds__(256) build_csr(
        const unsigned int* __restrict__ region, const int* __restrict__ gcur,
        int* __restrict__ cnt, unsigned short* __restrict__ csr_pad, int N) {
    __shared__ unsigned short lcsr[128 * MAXDEG];   // 16 KB
    __shared__ int lcnt[128];
    int b = blockIdx.x, tid = threadIdx.x;
    if (tid < 128) lcnt[tid] = 0;
    __syncthreads();
    int ecnt = gcur[b]; if (ecnt > CAP) ecnt = CAP;
    const unsigned int* reg = region + (size_t)b * CAP;
    for (int i = tid; i < ecnt; i += 256) {
        unsigned v = reg[i];
        int dloc = (int)(v >> 16), s = (int)(v & 0xFFFFu);
        int r = atomicAdd(&lcnt[dloc], 1);
        if (r < MAXDEG) lcsr[dloc * MAXDEG + r] = (unsigned short)s;
    }
    __syncthreads();
    int n0 = b << BSHIFT;
    int nb = N - n0; if (nb > 128) nb = 128;
    if (tid < nb) cnt[n0 + tid] = lcnt[tid];
    int4* gout = (int4*)(csr_pad + (size_t)n0 * MAXDEG);
    const int4* lin = (const int4*)lcsr;
    int tot = nb * 8;
    for (int i = tid; i < tot; i += 256) gout[i] = lin[i];
}

__global__ void __launch_bounds__(256) node_gemm_mfma(
        const float* __restrict__ x, const unsigned short* __restrict__ Bp1,
        const int* __restrict__ cnt, unsigned short* __restrict__ gbf, int NW) {
    __shared__ unsigned short sB[4096];   // 8 KB
    {
        const int4* gB = (const int4*)Bp1;
        int4* lB = (int4*)sB;
#pragma unroll
        for (int i = 0; i < 2; ++i)
            lB[threadIdx.x + i * 256] = gB[threadIdx.x + i * 256];
    }
    __syncthreads();
    int wid = blockIdx.x * 4 + (threadIdx.x >> 6);
    if (wid >= NW) return;
    int lane = threadIdx.x & 63, m = lane & 15, quad = lane >> 4;
    int r0 = wid * 16;
    f32x4 acc[4];
#pragma unroll
    for (int t = 0; t < 4; ++t) acc[t] = (f32x4){0.f, 0.f, 0.f, 0.f};
    const bf16x8* bp = (const bf16x8*)sB;
#pragma unroll
    for (int s = 0; s < 2; ++s) {
        const float4* xp = (const float4*)(x + (size_t)(r0 + m) * 64 + s * 32 + quad * 8);
        float4 v0 = xp[0], v1 = xp[1];
        bf16x8 a;
        a[0] = (short)f2b(v0.x); a[1] = (short)f2b(v0.y);
        a[2] = (short)f2b(v0.z); a[3] = (short)f2b(v0.w);
        a[4] = (short)f2b(v1.x); a[5] = (short)f2b(v1.y);
        a[6] = (short)f2b(v1.z); a[7] = (short)f2b(v1.w);
#pragma unroll
        for (int t = 0; t < 4; ++t)
            acc[t] = __builtin_amdgcn_mfma_f32_16x16x32_bf16(
                a, bp[(s * 4 + t) * 64 + lane], acc[t], 0, 0, 0);
    }
#pragma unroll
    for (int reg = 0; reg < 4; ++reg) {
        int row = r0 + quad * 4 + reg;
        float di = rsqrtf((float)cnt[row] + 1.0f);
#pragma unroll
        for (int t = 0; t < 4; ++t)
            gbf[(size_t)row * 64 + t * 16 + m] = f2b(acc[t][reg] * di);
    }
}

__global__ void __launch_bounds__(256) gather_finalize(
        const unsigned short* __restrict__ gbf, const unsigned short* __restrict__ csr_pad,
        const int* __restrict__ cnt, const float* __restrict__ b1,
        unsigned short* __restrict__ hbf, int N) {
    int wid = blockIdx.x * 4 + (threadIdx.x >> 6);
    if (wid >= N) return;
    int lane = threadIdx.x & 63;
    int n8 = lane >> 3, c8 = lane & 7;
    int deg = cnt[wid];
    if (deg > MAXDEG) deg = MAXDEG;
    size_t base = (size_t)wid << 6;
    const int4* gb4 = (const int4*)gbf;
    float a[8];
#pragma unroll
    for (int k = 0; k < 8; ++k) a[k] = 0.f;
    for (int j0 = 0; j0 < deg; j0 += 64) {
        int nidx = j0 + lane;
        int sidx = (nidx < deg) ? (int)csr_pad[base + nidx] : 0;
        int c = deg - j0; if (c > 64) c = 64;
        for (int step = 0; step * 8 < c; ++step) {
            int nn = step * 8 + n8;
            int srow = __shfl(sidx, nn, 64);
            int4 u = make_int4(0, 0, 0, 0);
            if (nn < c) u = gb4[(size_t)srow * 8 + c8];
            a[0] += __uint_as_float((unsigned)u.x << 16);
            a[1] += __uint_as_float((unsigned)u.x & 0xffff0000u);
            a[2] += __uint_as_float((unsigned)u.y << 16);
            a[3] += __uint_as_float((unsigned)u.y & 0xffff0000u);
            a[4] += __uint_as_float((unsigned)u.z << 16);
            a[5] += __uint_as_float((unsigned)u.z & 0xffff0000u);
            a[6] += __uint_as_float((unsigned)u.w << 16);
            a[7] += __uint_as_float((unsigned)u.w & 0xffff0000u);
        }
    }
#pragma unroll
    for (int mask = 8; mask < 64; mask <<= 1) {
#pragma unroll
        for (int k = 0; k < 8; ++k) a[k] += __shfl_xor(a[k], mask, 64);
    }
    {
        int4 u = gb4[(size_t)wid * 8 + c8];
        a[0] += __uint_as_float((unsigned)u.x << 16);
        a[1] += __uint_as_float((unsigned)u.x & 0xffff0000u);
        a[2] += __uint_as_float((unsigned)u.y << 16);
        a[3] += __uint_as_float((unsigned)u.y & 0xffff0000u);
        a[4] += __uint_as_float((unsigned)u.z << 16);
        a[5] += __uint_as_float((unsigned)u.z & 0xffff0000u);
        a[6] += __uint_as_float((unsigned)u.w << 16);
        a[7] += __uint_as_float((unsigned)u.w & 0xffff0000u);
    }
    if (n8 == 0) {
        float di = rsqrtf((float)deg + 1.0f);
        const float4* bv = (const float4*)(b1 + c8 * 8);
        float4 b0 = bv[0], b14 = bv[1];
        float h0 = di * a[0] + b0.x,  h1 = di * a[1] + b0.y;
        float h2 = di * a[2] + b0.z,  h3 = di * a[3] + b0.w;
        float h4 = di * a[4] + b14.x, h5 = di * a[5] + b14.y;
        float h6 = di * a[6] + b14.z, h7 = di * a[7] + b14.w;
        h0 = h0 > 0.f ? h0 : 0.f; h1 = h1 > 0.f ? h1 : 0.f;
        h2 = h2 > 0.f ? h2 : 0.f; h3 = h3 > 0.f ? h3 : 0.f;
        h4 = h4 > 0.f ? h4 : 0.f; h5 = h5 > 0.f ? h5 : 0.f;
        h6 = h6 > 0.f ? h6 : 0.f; h7 = h7 > 0.f ? h7 : 0.f;
        int4 w;
        w.x = (int)((unsigned)f2b(h0) | ((unsigned)f2b(h1) << 16));
        w.y = (int)((unsigned)f2b(h2) | ((unsigned)f2b(h3) << 16));
        w.z = (int)((unsigned)f2b(h4) | ((unsigned)f2b(h5) << 16));
        w.w = (int)((unsigned)f2b(h6) | ((unsigned)f2b(h7) << 16));
        ((int4*)hbf)[(size_t)wid * 8 + c8] = w;
    }
}

__global__ void __launch_bounds__(256, 8) edge_mlp_mfma(
        const unsigned short* __restrict__ hbf, const float* __restrict__ ea,
        const int* __restrict__ src, const int* __restrict__ dst,
        const unsigned short* __restrict__ Bp,
        const float* __restrict__ bm1, const float* __restrict__ Wm2,
        const float* __restrict__ bm2, float* __restrict__ out, int E) {
    __shared__ unsigned short sB[10240];   // 20 KB
    {
        const int4* gB = (const int4*)Bp;
        int4* lB = (int4*)sB;
#pragma unroll
        for (int i = 0; i < 5; ++i)
            lB[threadIdx.x + i * 256] = gB[threadIdx.x + i * 256];
    }
    __syncthreads();
    int lane = threadIdx.x & 63;
    int wave = threadIdx.x >> 6;
    int m = lane & 15, quad = lane >> 4;
    int e0 = (blockIdx.x * 4 + wave) * 16;
    if (e0 >= E) return;
    int e = e0 + m;
    int ec = e < E ? e : E - 1;
    int si = src[ec], di = dst[ec];
    bf16x8 af[5];
    af[0] = *(const bf16x8*)(hbf + (size_t)si * 64 + quad * 8);
    af[1] = *(const bf16x8*)(hbf + (size_t)si * 64 + 32 + quad * 8);
    af[2] = *(const bf16x8*)(hbf + (size_t)di * 64 + quad * 8);
    af[3] = *(const bf16x8*)(hbf + (size_t)di * 64 + 32 + quad * 8);
    if (quad < 2) {
        const float4* ep = (const float4*)(ea + (size_t)ec * 16 + quad * 8);
        float4 v0 = ep[0], v1 = ep[1];
        af[4][0] = (short)f2b(v0.x); af[4][1] = (short)f2b(v0.y);
        af[4][2] = (short)f2b(v0.z); af[4][3] = (short)f2b(v0.w);
        af[4][4] = (short)f2b(v1.x); af[4][5] = (short)f2b(v1.y);
        af[4][6] = (short)f2b(v1.z); af[4][7] = (short)f2b(v1.w);
    } else {
#pragma unroll
        for (int j = 0; j < 8; ++j) af[4][j] = 0;
    }
    __builtin_amdgcn_sched_barrier(0);
    f32x4 acc[4];
#pragma unroll
    for (int t = 0; t < 4; ++t) acc[t] = (f32x4){0.f, 0.f, 0.f, 0.f};
    const bf16x8* bp = (const bf16x8*)sB;
#pragma unroll
    for (int s = 0; s < 5; ++s) {
#pragma unroll
        for (int t = 0; t < 4; ++t)
            acc[t] = __builtin_amdgcn_mfma_f32_16x16x32_bf16(
                af[s], bp[(s * 4 + t) * 64 + lane], acc[t], 0, 0, 0);
    }
    float w2[4], bb[4];
#pragma unroll
    for (int t = 0; t < 4; ++t) {
        int col = t * 16 + m;
        bb[t] = bm1[col];
        w2[t] = Wm2[col];
    }
    float pr[4];
#pragma unroll
    for (int r = 0; r < 4; ++r) {
        float sum = 0.0f;
#pragma unroll
        for (int t = 0; t < 4; ++t) {
            float hv = acc[t][r] + bb[t];
            sum += (hv > 0.0f ? hv : 0.0f) * w2[t];
        }
        pr[r] = sum;
    }
#pragma unroll
    for (int off = 1; off < 16; off <<= 1) {
#pragma unroll
        for (int r = 0; r < 4; ++r) pr[r] += __shfl_xor(pr[r], off, 64);
    }
    float b2 = bm2[0];
    if (m < 4) {
        int eo = e0 + quad * 4 + m;
        if (eo < E) out[eo] = 1.0f / (1.0f + __expf(-(pr[m] + b2)));
    }
}

// ================================ launcher =================================
extern "C" void kernel_launch(void* const* d_in, const int* in_sizes, int n_in,
                              void* d_out, int out_size, void* d_ws, size_t ws_size,
                              hipStream_t stream) {
    const float* x   = (const float*)d_in[0];
    const int*   src = (const int*)d_in[1];
    const int*   dst = (const int*)d_in[2];
    const float* ea  = (const float*)d_in[3];
    const float* W1  = (const float*)d_in[4];
    const float* b1  = (const float*)d_in[5];
    const float* Wm1 = (const float*)d_in[6];
    const float* bm1 = (const float*)d_in[7];
    const float* Wm2 = (const float*)d_in[8];
    const float* bm2 = (const float*)d_in[9];
    float* out = (float*)d_out;

    int N = in_sizes[0] / 64;   // 50000
    int E = in_sizes[1];        // 800000

    // ws layout (~19.5 MB; region aliases hbf — dead before ph4 writes hbf):
    char* p = (char*)d_ws;
    unsigned short* gbf     = (unsigned short*)p; p += (size_t)N * 64 * 2;      // 6.4 MB
    unsigned short* hbf     = (unsigned short*)p; p += (size_t)N * 64 * 2;      // 6.4 MB
    unsigned short* csr_pad = (unsigned short*)p; p += (size_t)N * MAXDEG * 2;  // 6.4 MB
    int*            cnt     = (int*)p;            p += (size_t)N * 4;           // 0.2 MB
    int*            gcur    = (int*)p;            p += (size_t)((NBUCK * 4 + 15) / 16) * 16;
    unsigned short* Bp      = (unsigned short*)p; p += 10240 * 2;
    unsigned short* Bp1     = (unsigned short*)p; p += 4096 * 2;
    unsigned int*   region  = (unsigned int*)hbf;   // 4.0 MB alias (< 6.4 MB)

    // One-time cooperative capability probe (capture-safe queries, cached).
    static int coop_grid = -1;   // -1 unknown, 0 disabled, >0 grid size
    if (coop_grid < 0) {
        int nb = 0;
        hipError_t qe = hipOccupancyMaxActiveBlocksPerMultiprocessor(
            &nb, fused_gcn, 256, 0);
        if (qe == hipSuccess && nb > 0) {
            int dev = 0;
            hipGetDevice(&dev);
            hipDeviceProp_t prop;
            if (hipGetDeviceProperties(&prop, dev) == hipSuccess &&
                prop.multiProcessorCount > 0) {
                long g = (long)nb * prop.multiProcessorCount;
                if (g > 2048) g = 2048;
                coop_grid = (g >= 256) ? (int)g : 0;
            } else coop_grid = 0;
        } else coop_grid = 0;
    }

    hipMemsetAsync(gcur, 0, NBUCK * sizeof(int), stream);

    if (coop_grid > 0) {
        void* args[] = { &x, &src, &dst, &ea, &W1, &b1, &Wm1, &bm1, &Wm2, &bm2,
                         &out, &gbf, &hbf, &csr_pad, &region, &cnt, &gcur,
                         &Bp, &Bp1, &N, &E };
        hipError_t le = hipLaunchCooperativeKernel(
            (void*)fused_gcn, dim3((unsigned)coop_grid), dim3(256), args, 0, stream);
        if (le == hipSuccess) return;
        coop_grid = 0;   // permanent fallback from here on
    }

    // Split fallback (R3-proven, 128-node-bucket geometry).
    bin_pack<<<NCHUNK + PACKB, 256, 0, stream>>>(dst, src, region, gcur, E, NCHUNK,
                                                 Wm1, W1, Bp, Bp1);
    build_csr<<<NBUCK, 256, 0, stream>>>(region, gcur, cnt, csr_pad, N);
    node_gemm_mfma<<<(N / 16 + 3) / 4, 256, 0, stream>>>(x, Bp1, cnt, gbf, N / 16);
    gather_finalize<<<(N + 3) / 4, 256, 0, stream>>>(gbf, csr_pad, cnt, b1, hbf, N);
    edge_mlp_mfma<<<(E + 63) / 64, 256, 0, stream>>>(hbf, ea, src, dst, Bp,
                                                     bm1, Wm2, bm2, out, E);
}

// Round 6
// 194.585 us; speedup vs baseline: 2.5783x; 2.5783x over previous
//
#include <hip/hip_runtime.h>
#include <math.h>

// Problem constants: N=50000, E=800000, D=H=64, ED=16.
// Pipeline v7 (split, statically compressed; coop fusion ABANDONED):
//   memset gcur (391 ints)
//   K1 bin_gemm_pack: blocks [0,391) bin edges by dst-bucket into region;
//      blocks [391,1173) node GEMM (RAW h, self-packed W1 in LDS);
//      blocks [1173,1213) pack Wm1->Bp for edge MLP.
//   K2 build_csr: bucket per block, CSR+cnt via LDS, streamed out.
//   K3 gather: hbf = bf16(relu(dd*(sum_s dinv_s*h_s + dd*h_d) + b1)),
//      dinv_s = rsqrt(cnt[srow]+1) applied per neighbor (VALU was idle).
//   K4 edge_mlp: out = sigmoid(relu([h_s|h_d|ea]@Wm1+bm1)@Wm2+bm2).
//
// R5 LESSON (decisive): cooperative fused kernel passed but 679us/dispatch.
// Work integrals matched split (VALU 4.1%x680=28us, Mfma 1%x680=6.7us,
// FETCH 129MB) -> ~550us pure idle = 4 grid.sync()s ~130us EACH at 1280
// blocks (cross-XCD coherence-point spin). cg::grid.sync is O(100us) on
// this platform. NEVER use grid-wide sync here; dependency levels must be
// separate dispatches.
// R3 CORRECTION: dispatch gap ~5us/boundary (not 16); the rest of the
// 194us is real kernel time in bin/build/gemm/gather.
//
// LESSONS ENCODED:
//  - hbf must NOT alias gbf (cross-block RW race). region aliases hbf OK
//    (region dead after K2; hbf written K3).
//  - edge_mlp pinned ~48.5us across 6 variants: random-row fetch bound
//    (1.6M x 128B from L2/L3). Don't tune it.
//  - R2: random-scatter cost is per-EVENT (~55B/edge) -> keep stores binned.
//  - Per-block weight self-pack is fine for FEW blocks reading SMALL W
//    (782 x 16KB L2-broadcast); the old "3x regression" was 12500-block
//    edge_mlp self-pack (450MB + serial pre-MFMA work).
//  - cnt holds TRUE degree (count unconditional, store guarded at 64);
//    max indeg ~45 (seed 0); CAP=2560 = mean 2046 + 11 sigma.

typedef __attribute__((ext_vector_type(8))) short bf16x8;
typedef __attribute__((ext_vector_type(4))) float f32x4;

#define MAXDEG 64
#define BSHIFT 7           // 128 nodes per bucket
#define BMASK 127
#define NBUCK 391          // ceil(50000/128)
#define CAP 2560           // per-bucket region capacity (mean 2046 + 11s)
#define CHUNK 2048         // edges per bin block
#define BINB 391           // bin blocks = ceil(800000/2048)
#define GEMB 782           // gemm blocks = ceil(3125 wave-tiles / 4)
#define BPB 40             // Bp pack blocks = 10240/256

__device__ __forceinline__ unsigned short f2b(float f) {
    unsigned u = __float_as_uint(f);
    unsigned r = (u + 0x7FFFu + ((u >> 16) & 1u)) >> 16;   // RNE
    return (unsigned short)r;
}

// K1: three independent block roles in one dispatch (bin is memory/atomic
// bound, gemm is MFMA bound -> good CU co-scheduling; no cross-block deps).
__global__ void __launch_bounds__(256) bin_gemm_pack(
        const int* __restrict__ dst, const int* __restrict__ src,
        unsigned int* __restrict__ region, int* __restrict__ gcur, int E,
        const float* __restrict__ x, const float* __restrict__ W1,
        unsigned short* __restrict__ gbf,
        const float* __restrict__ Wm1, unsigned short* __restrict__ Bp, int N) {
    __shared__ __align__(16) char smem[8192];
    const int bid = blockIdx.x, tid = threadIdx.x;

    if (bid < BINB) {
        // ---- bin edges into dst-buckets ----
        int* lc = (int*)smem;
        int* gb = lc + NBUCK;
        for (int i = tid; i < NBUCK; i += 256) lc[i] = 0;
        __syncthreads();
        int base = bid * CHUNK + tid * 8;   // 8 consecutive edges/thread
        unsigned key[8], val[8];
#pragma unroll
        for (int k = 0; k < 8; ++k) {
            int e = base + k;
            key[k] = 0xFFFFFFFFu;
            if (e < E) {
                int d = dst[e], s = src[e];
                int b = d >> BSHIFT;
                int r = atomicAdd(&lc[b], 1);          // LDS atomic: local rank
                key[k] = (unsigned)b | ((unsigned)r << 9);   // b<512, r<2048
                val[k] = ((unsigned)(d & BMASK) << 16) | (unsigned)s;
            }
        }
        __syncthreads();
        for (int i = tid; i < NBUCK; i += 256) {
            int t = lc[i];
            gb[i] = t ? atomicAdd(&gcur[i], t) : 0;    // ONE global atomic/bucket
        }
        __syncthreads();
#pragma unroll
        for (int k = 0; k < 8; ++k) {
            if (key[k] != 0xFFFFFFFFu) {
                int b = (int)(key[k] & 511u), r = (int)(key[k] >> 9);
                int idx = gb[b] + r;
                if (idx < CAP) region[(size_t)b * CAP + idx] = val[k];
            }
        }
    } else if (bid < BINB + GEMB) {
        // ---- node GEMM, RAW h (no dinv), self-packed W1 ----
        unsigned short* sB = (unsigned short*)smem;    // 8 KB
        for (int i = tid; i < 4096; i += 256) {
            int j = i & 7, ln = (i >> 3) & 63, t = (i >> 9) & 3, s = i >> 11;
            int k = s * 32 + (ln >> 4) * 8 + j, col = t * 16 + (ln & 15);
            sB[i] = f2b(W1[k * 64 + col]);
        }
        __syncthreads();
        int wid = (bid - BINB) * 4 + (tid >> 6);
        int NWT = N / 16;   // 3125
        if (wid < NWT) {
            int lane = tid & 63, m = lane & 15, quad = lane >> 4;
            int r0 = wid * 16;
            f32x4 acc[4];
#pragma unroll
            for (int t = 0; t < 4; ++t) acc[t] = (f32x4){0.f, 0.f, 0.f, 0.f};
            const bf16x8* bp = (const bf16x8*)sB;
#pragma unroll
            for (int s = 0; s < 2; ++s) {
                const float4* xp = (const float4*)(x + (size_t)(r0 + m) * 64 + s * 32 + quad * 8);
                float4 v0 = xp[0], v1 = xp[1];
                bf16x8 a;
                a[0] = (short)f2b(v0.x); a[1] = (short)f2b(v0.y);
                a[2] = (short)f2b(v0.z); a[3] = (short)f2b(v0.w);
                a[4] = (short)f2b(v1.x); a[5] = (short)f2b(v1.y);
                a[6] = (short)f2b(v1.z); a[7] = (short)f2b(v1.w);
#pragma unroll
                for (int t = 0; t < 4; ++t)
                    acc[t] = __builtin_amdgcn_mfma_f32_16x16x32_bf16(
                        a, bp[(s * 4 + t) * 64 + lane], acc[t], 0, 0, 0);
            }
#pragma unroll
            for (int reg = 0; reg < 4; ++reg) {
                int row = r0 + quad * 4 + reg;
#pragma unroll
                for (int t = 0; t < 4; ++t)
                    gbf[(size_t)row * 64 + t * 16 + m] = f2b(acc[t][reg]);
            }
        }
    } else {
        // ---- pack Wm1 [144x64] -> Bp (5 K-steps, K padded 160) ----
        int idx = (bid - BINB - GEMB) * 256 + tid;
        if (idx < 10240) {
            int j = idx & 7, ln = (idx >> 3) & 63, t = (idx >> 9) & 3, s = idx >> 11;
            int k = s * 32 + (ln >> 4) * 8 + j, col = t * 16 + (ln & 15);
            float v = (k < 144) ? Wm1[k * 64 + col] : 0.0f;
            Bp[idx] = f2b(v);
        }
    }
}

// K2: block b builds padded CSR for nodes [b*128, b*128+nb) in LDS, writes
// cnt + csr_pad as sequential streams.
__global__ void __launch_bounds__(256) build_csr(
        const unsigned int* __restrict__ region, const int* __restrict__ gcur,
        int* __restrict__ cnt, unsigned short* __restrict__ csr_pad, int N) {
    __shared__ unsigned short lcsr[128 * MAXDEG];   // 16 KB
    __shared__ int lcnt[128];
    int b = blockIdx.x, tid = threadIdx.x;
    if (tid < 128) lcnt[tid] = 0;
    __syncthreads();
    int ecnt = gcur[b]; if (ecnt > CAP) ecnt = CAP;
    const unsigned int* reg = region + (size_t)b * CAP;
    for (int i = tid; i < ecnt; i += 256) {
        unsigned v = reg[i];
        int dloc = (int)(v >> 16), s = (int)(v & 0xFFFFu);
        int r = atomicAdd(&lcnt[dloc], 1);          // true degree counted
        if (r < MAXDEG) lcsr[dloc * MAXDEG + r] = (unsigned short)s;
    }
    __syncthreads();
    int n0 = b << BSHIFT;
    int nb = N - n0; if (nb > 128) nb = 128;
    if (tid < nb) cnt[n0 + tid] = lcnt[tid];
    int4* gout = (int4*)(csr_pad + (size_t)n0 * MAXDEG);
    const int4* lin = (const int4*)lcsr;
    int tot = nb * 8;   // nb rows x 64 ushorts
    for (int i = tid; i < tot; i += 256) gout[i] = lin[i];
}

// K3: wave per node; 8 neighbors/step; per-neighbor dinv_s applied on the
// fly (gbf holds RAW h). h = dd*(sum_s ds*h_s + dd*h_d) + b1, relu, bf16.
__global__ void __launch_bounds__(256) gather_finalize(
        const unsigned short* __restrict__ gbf, const unsigned short* __restrict__ csr_pad,
        const int* __restrict__ cnt, const float* __restrict__ b1,
        unsigned short* __restrict__ hbf, int N) {
    int wid = blockIdx.x * 4 + (threadIdx.x >> 6);
    if (wid >= N) return;
    int lane = threadIdx.x & 63;
    int n8 = lane >> 3, c8 = lane & 7;
    int deg = cnt[wid];
    if (deg > MAXDEG) deg = MAXDEG;   // never hit: max indeg ~45
    size_t base = (size_t)wid << 6;
    const int4* gb4 = (const int4*)gbf;    // row stride = 8 int4 (128 B)
    float a[8];
#pragma unroll
    for (int k = 0; k < 8; ++k) a[k] = 0.f;

    for (int j0 = 0; j0 < deg; j0 += 64) {
        int nidx = j0 + lane;
        int sidx = (nidx < deg) ? (int)csr_pad[base + nidx] : 0;
        int c = deg - j0; if (c > 64) c = 64;
        for (int step = 0; step * 8 < c; ++step) {
            int nn = step * 8 + n8;
            int srow = __shfl(sidx, nn, 64);
            int4 u = make_int4(0, 0, 0, 0);
            float ds = 0.f;
            if (nn < c) {
                u = gb4[(size_t)srow * 8 + c8];
                ds = rsqrtf((float)cnt[srow] + 1.0f);
            }
            a[0] += ds * __uint_as_float((unsigned)u.x << 16);
            a[1] += ds * __uint_as_float((unsigned)u.x & 0xffff0000u);
            a[2] += ds * __uint_as_float((unsigned)u.y << 16);
            a[3] += ds * __uint_as_float((unsigned)u.y & 0xffff0000u);
            a[4] += ds * __uint_as_float((unsigned)u.z << 16);
            a[5] += ds * __uint_as_float((unsigned)u.z & 0xffff0000u);
            a[6] += ds * __uint_as_float((unsigned)u.w << 16);
            a[7] += ds * __uint_as_float((unsigned)u.w & 0xffff0000u);
        }
    }
    // reduce across the 8 neighbor-groups
#pragma unroll
    for (int mask = 8; mask < 64; mask <<= 1) {
#pragma unroll
        for (int k = 0; k < 8; ++k) a[k] += __shfl_xor(a[k], mask, 64);
    }
    float dd = rsqrtf((float)deg + 1.0f);
    {   // self loop (add ONCE, after reduction — every lane has full sum)
        int4 u = gb4[(size_t)wid * 8 + c8];
        a[0] += dd * __uint_as_float((unsigned)u.x << 16);
        a[1] += dd * __uint_as_float((unsigned)u.x & 0xffff0000u);
        a[2] += dd * __uint_as_float((unsigned)u.y << 16);
        a[3] += dd * __uint_as_float((unsigned)u.y & 0xffff0000u);
        a[4] += dd * __uint_as_float((unsigned)u.z << 16);
        a[5] += dd * __uint_as_float((unsigned)u.z & 0xffff0000u);
        a[6] += dd * __uint_as_float((unsigned)u.w << 16);
        a[7] += dd * __uint_as_float((unsigned)u.w & 0xffff0000u);
    }
    if (n8 == 0) {
        const float4* bv = (const float4*)(b1 + c8 * 8);
        float4 b0 = bv[0], b14 = bv[1];
        float h0 = dd * a[0] + b0.x,  h1 = dd * a[1] + b0.y;
        float h2 = dd * a[2] + b0.z,  h3 = dd * a[3] + b0.w;
        float h4 = dd * a[4] + b14.x, h5 = dd * a[5] + b14.y;
        float h6 = dd * a[6] + b14.z, h7 = dd * a[7] + b14.w;
        h0 = h0 > 0.f ? h0 : 0.f; h1 = h1 > 0.f ? h1 : 0.f;
        h2 = h2 > 0.f ? h2 : 0.f; h3 = h3 > 0.f ? h3 : 0.f;
        h4 = h4 > 0.f ? h4 : 0.f; h5 = h5 > 0.f ? h5 : 0.f;
        h6 = h6 > 0.f ? h6 : 0.f; h7 = h7 > 0.f ? h7 : 0.f;
        int4 w;
        w.x = (int)((unsigned)f2b(h0) | ((unsigned)f2b(h1) << 16));
        w.y = (int)((unsigned)f2b(h2) | ((unsigned)f2b(h3) << 16));
        w.z = (int)((unsigned)f2b(h4) | ((unsigned)f2b(h5) << 16));
        w.w = (int)((unsigned)f2b(h6) | ((unsigned)f2b(h7) << 16));
        ((int4*)hbf)[(size_t)wid * 8 + c8] = w;
    }
}

// K4: one wave per 16 edges; K=160 (144 padded), 4 N-tiles. Pre-packed Bp
// staged via int4; all 5 A-frags loaded before the MFMA phase.
__global__ void __launch_bounds__(256, 8) edge_mlp_mfma(
        const unsigned short* __restrict__ hbf, const float* __restrict__ ea,
        const int* __restrict__ src, const int* __restrict__ dst,
        const unsigned short* __restrict__ Bp,
        const float* __restrict__ bm1, const float* __restrict__ Wm2,
        const float* __restrict__ bm2, float* __restrict__ out, int E) {
    __shared__ unsigned short sB[10240];   // 20 KB
    {
        const int4* gB = (const int4*)Bp;
        int4* lB = (int4*)sB;
#pragma unroll
        for (int i = 0; i < 5; ++i)
            lB[threadIdx.x + i * 256] = gB[threadIdx.x + i * 256];
    }
    __syncthreads();
    int lane = threadIdx.x & 63;
    int wave = threadIdx.x >> 6;
    int m = lane & 15, quad = lane >> 4;
    int e0 = (blockIdx.x * 4 + wave) * 16;
    if (e0 >= E) return;
    int e = e0 + m;
    int ec = e < E ? e : E - 1;
    int si = src[ec], di = dst[ec];
    bf16x8 af[5];
    af[0] = *(const bf16x8*)(hbf + (size_t)si * 64 + quad * 8);
    af[1] = *(const bf16x8*)(hbf + (size_t)si * 64 + 32 + quad * 8);
    af[2] = *(const bf16x8*)(hbf + (size_t)di * 64 + quad * 8);
    af[3] = *(const bf16x8*)(hbf + (size_t)di * 64 + 32 + quad * 8);
    if (quad < 2) {
        const float4* ep = (const float4*)(ea + (size_t)ec * 16 + quad * 8);
        float4 v0 = ep[0], v1 = ep[1];
        af[4][0] = (short)f2b(v0.x); af[4][1] = (short)f2b(v0.y);
        af[4][2] = (short)f2b(v0.z); af[4][3] = (short)f2b(v0.w);
        af[4][4] = (short)f2b(v1.x); af[4][5] = (short)f2b(v1.y);
        af[4][6] = (short)f2b(v1.z); af[4][7] = (short)f2b(v1.w);
    } else {
#pragma unroll
        for (int j = 0; j < 8; ++j) af[4][j] = 0;
    }
    __builtin_amdgcn_sched_barrier(0);
    f32x4 acc[4];
#pragma unroll
    for (int t = 0; t < 4; ++t) acc[t] = (f32x4){0.f, 0.f, 0.f, 0.f};
    const bf16x8* bp = (const bf16x8*)sB;
#pragma unroll
    for (int s = 0; s < 5; ++s) {
#pragma unroll
        for (int t = 0; t < 4; ++t)
            acc[t] = __builtin_amdgcn_mfma_f32_16x16x32_bf16(
                af[s], bp[(s * 4 + t) * 64 + lane], acc[t], 0, 0, 0);
    }
    float w2[4], bb[4];
#pragma unroll
    for (int t = 0; t < 4; ++t) {
        int col = t * 16 + m;
        bb[t] = bm1[col];
        w2[t] = Wm2[col];
    }
    float pr[4];
#pragma unroll
    for (int r = 0; r < 4; ++r) {
        float sum = 0.0f;
#pragma unroll
        for (int t = 0; t < 4; ++t) {
            float hv = acc[t][r] + bb[t];
            sum += (hv > 0.0f ? hv : 0.0f) * w2[t];
        }
        pr[r] = sum;
    }
#pragma unroll
    for (int off = 1; off < 16; off <<= 1) {
#pragma unroll
        for (int r = 0; r < 4; ++r) pr[r] += __shfl_xor(pr[r], off, 64);
    }
    float b2 = bm2[0];
    if (m < 4) {
        int eo = e0 + quad * 4 + m;
        if (eo < E) out[eo] = 1.0f / (1.0f + __expf(-(pr[m] + b2)));
    }
}

// ================================ launcher =================================
extern "C" void kernel_launch(void* const* d_in, const int* in_sizes, int n_in,
                              void* d_out, int out_size, void* d_ws, size_t ws_size,
                              hipStream_t stream) {
    const float* x   = (const float*)d_in[0];
    const int*   src = (const int*)d_in[1];
    const int*   dst = (const int*)d_in[2];
    const float* ea  = (const float*)d_in[3];
    const float* W1  = (const float*)d_in[4];
    const float* b1  = (const float*)d_in[5];
    const float* Wm1 = (const float*)d_in[6];
    const float* bm1 = (const float*)d_in[7];
    const float* Wm2 = (const float*)d_in[8];
    const float* bm2 = (const float*)d_in[9];
    float* out = (float*)d_out;

    int N = in_sizes[0] / 64;   // 50000
    int E = in_sizes[1];        // 800000

    // ws layout (~19.5 MB; region aliases hbf — dead before K3 writes hbf):
    char* p = (char*)d_ws;
    unsigned short* gbf     = (unsigned short*)p; p += (size_t)N * 64 * 2;      // 6.4 MB
    unsigned short* hbf     = (unsigned short*)p; p += (size_t)N * 64 * 2;      // 6.4 MB
    unsigned short* csr_pad = (unsigned short*)p; p += (size_t)N * MAXDEG * 2;  // 6.4 MB
    int*            cnt     = (int*)p;            p += (size_t)N * 4;           // 0.2 MB
    int*            gcur    = (int*)p;            p += (size_t)((NBUCK * 4 + 15) / 16) * 16;
    unsigned short* Bp      = (unsigned short*)p; p += 10240 * 2;
    unsigned int*   region  = (unsigned int*)hbf;   // 4.0 MB alias (< 6.4 MB)

    hipMemsetAsync(gcur, 0, NBUCK * sizeof(int), stream);
    bin_gemm_pack<<<BINB + GEMB + BPB, 256, 0, stream>>>(
        dst, src, region, gcur, E, x, W1, gbf, Wm1, Bp, N);
    build_csr<<<NBUCK, 256, 0, stream>>>(region, gcur, cnt, csr_pad, N);
    gather_finalize<<<(N + 3) / 4, 256, 0, stream>>>(gbf, csr_pad, cnt, b1, hbf, N);
    edge_mlp_mfma<<<(E + 63) / 64, 256, 0, stream>>>(hbf, ea, src, dst, Bp,
                                                     bm1, Wm2, bm2, out, E);
}

// Round 7
// 190.736 us; speedup vs baseline: 2.6304x; 1.0202x over previous
//
#include <hip/hip_runtime.h>
#include <math.h>

// Problem constants: N=50000, E=800000, D=H=64, ED=16.
// Pipeline v8 (split; bin now LDS-bucket-sorted -> coalesced region runs):
//   memset gcur (391 ints)
//   K1 bin_gemm_pack: blocks [0,196) bin 4096-edge chunks: LDS histogram ->
//      rank, 512-wide scan, LDS scatter-sort, then COALESCED run writes to
//      region (77k events vs 800k scattered stores).
//      blocks [196,978) node GEMM (RAW h, self-packed W1 in LDS);
//      blocks [978,1018) pack Wm1->Bp.
//   K2 build_csr: bucket per block, CSR+cnt via LDS, streamed out.
//   K3 gather: dinv_s prefetched 64-wide (cnt load + rsqrt hoisted out of
//      the dependent inner loop; float shuffled alongside index).
//   K4 edge_mlp: unchanged (pinned 48.5us, random-row fetch bound).
//
// R6 LESSON: dispatch-gap theory DEAD (R3 194.1 == R6 194.6 across two
// structures; hiding gemm + removing a boundary = 0). Missing ~50us vs
// cost model is INSIDE kernels. Prime suspect: bin's 800k scattered 4B
// region stores = the SAME per-event pathology as R2's hist (44MB/50us);
// I removed the atomics but kept the scattered stores. Fix = sort-in-LDS,
// write runs. Secondary: R6 put 800k random cnt loads in gather's inner
// dependent loop (likely ate the structural savings -> R6==R3).
// R5 LESSON: cg::grid.sync is O(100us)/sync here. Never.
//
// LESSONS ENCODED:
//  - hbf must NOT alias gbf. region aliases hbf OK (dead after K2).
//  - edge_mlp pinned ~48.5us across 6 variants. Don't tune it.
//  - R2: random-scatter cost is per-EVENT; coalesce or bin ALL stores.
//  - cnt holds TRUE degree; max indeg ~45 (seed 0); CAP=2560 = +11 sigma.

typedef __attribute__((ext_vector_type(8))) short bf16x8;
typedef __attribute__((ext_vector_type(4))) float f32x4;

#define MAXDEG 64
#define BSHIFT 7           // 128 nodes per bucket
#define BMASK 127
#define NBUCK 391          // ceil(50000/128)
#define CAP 2560           // per-bucket region capacity (mean 2046 + 11s)
#define CHUNK 4096         // edges per bin block (16/thread)
#define BINB 196           // ceil(800000/4096)
#define GEMB 782           // gemm blocks = ceil(3125 wave-tiles / 4)
#define BPB 40             // Bp pack blocks = 10240/256

__device__ __forceinline__ unsigned short f2b(float f) {
    unsigned u = __float_as_uint(f);
    unsigned r = (u + 0x7FFFu + ((u >> 16) & 1u)) >> 16;   // RNE
    return (unsigned short)r;
}

// K1: three independent block roles in one dispatch.
__global__ void __launch_bounds__(256) bin_gemm_pack(
        const int* __restrict__ dst, const int* __restrict__ src,
        unsigned int* __restrict__ region, int* __restrict__ gcur, int E,
        const float* __restrict__ x, const float* __restrict__ W1,
        unsigned short* __restrict__ gbf,
        const float* __restrict__ Wm1, unsigned short* __restrict__ Bp, int N) {
    // union: bin 32KB | gemm 8KB | pack 0
    __shared__ __align__(16) char smem[32768];
    const int bid = blockIdx.x, tid = threadIdx.x;

    if (bid < BINB) {
        // ---- bin role: histogram -> rank -> scan -> LDS sort -> run writes
        int* lc = (int*)smem;                         // [512] counts
        int* s0 = lc + 512;                           // [512] scan ping
        int* s1 = s0 + 512;                           // [512] scan pong
        int* gb = s1 + 512;                           // [512] global bases
        unsigned* lval = (unsigned*)(gb + 512);       // [4096] 16KB
        unsigned short* lbuk = (unsigned short*)(lval + 4096);  // [4096] 8KB

        for (int i = tid; i < 512; i += 256) lc[i] = 0;
        __syncthreads();

        // count + rank (16 edges/thread via 4x int4, coalesced)
        unsigned kb[16], kv[16];
#pragma unroll
        for (int j = 0; j < 4; ++j) {
            int i4 = bid * 1024 + j * 256 + tid;      // int4 index
            bool ok = (i4 * 4 < E);                   // E % 4 == 0
            int4 d4 = make_int4(0, 0, 0, 0), s4 = make_int4(0, 0, 0, 0);
            if (ok) { d4 = ((const int4*)dst)[i4]; s4 = ((const int4*)src)[i4]; }
            int dd[4] = {d4.x, d4.y, d4.z, d4.w};
            int ss[4] = {s4.x, s4.y, s4.z, s4.w};
#pragma unroll
            for (int k = 0; k < 4; ++k) {
                int idx = j * 4 + k;
                kb[idx] = 0xFFFFFFFFu;
                if (ok) {
                    int b = dd[k] >> BSHIFT;
                    int r = atomicAdd(&lc[b], 1);     // LDS atomic: local rank
                    kb[idx] = ((unsigned)b << 12) | (unsigned)r;   // b<512, r<4096
                    kv[idx] = ((unsigned)(dd[k] & BMASK) << 16) | (unsigned)ss[k];
                }
            }
        }
        __syncthreads();

        // inclusive scan (Hillis-Steele, 512 wide) -> exclusive bases in lb
        for (int i = tid; i < 512; i += 256) s0[i] = lc[i];
        __syncthreads();
        int* pin = s0; int* pout = s1;
        for (int off = 1; off < 512; off <<= 1) {
            for (int i = tid; i < 512; i += 256) {
                int v = pin[i];
                if (i >= off) v += pin[i - off];
                pout[i] = v;
            }
            __syncthreads();
            int* t = pin; pin = pout; pout = t;
        }
        int* lb = pout;   // free buffer
        for (int i = tid; i < 512; i += 256) lb[i] = pin[i] - lc[i];
        // global base reservation: ONE atomic per non-empty bucket
        for (int i = tid; i < NBUCK; i += 256) {
            int c = lc[i];
            gb[i] = c ? atomicAdd(&gcur[i], c) : 0;
        }
        __syncthreads();

        // scatter into LDS bucket-sorted order
#pragma unroll
        for (int idx = 0; idx < 16; ++idx) {
            if (kb[idx] != 0xFFFFFFFFu) {
                int b = (int)(kb[idx] >> 12), r = (int)(kb[idx] & 4095u);
                int pos = lb[b] + r;
                lval[pos] = kv[idx];
                lbuk[pos] = (unsigned short)b;
            }
        }
        __syncthreads();

        // write out: consecutive i within a bucket -> consecutive addresses
        int ne = E - bid * CHUNK; if (ne > CHUNK) ne = CHUNK;
        for (int i = tid; i < ne; i += 256) {
            int b = lbuk[i];
            int idx = gb[b] + (i - lb[b]);
            if (idx < CAP) region[(size_t)b * CAP + idx] = lval[i];
        }
    } else if (bid < BINB + GEMB) {
        // ---- node GEMM, RAW h (no dinv), self-packed W1 ----
        unsigned short* sB = (unsigned short*)smem;    // 8 KB
        for (int i = tid; i < 4096; i += 256) {
            int j = i & 7, ln = (i >> 3) & 63, t = (i >> 9) & 3, s = i >> 11;
            int k = s * 32 + (ln >> 4) * 8 + j, col = t * 16 + (ln & 15);
            sB[i] = f2b(W1[k * 64 + col]);
        }
        __syncthreads();
        int wid = (bid - BINB) * 4 + (tid >> 6);
        int NWT = N / 16;   // 3125
        if (wid < NWT) {
            int lane = tid & 63, m = lane & 15, quad = lane >> 4;
            int r0 = wid * 16;
            f32x4 acc[4];
#pragma unroll
            for (int t = 0; t < 4; ++t) acc[t] = (f32x4){0.f, 0.f, 0.f, 0.f};
            const bf16x8* bp = (const bf16x8*)sB;
#pragma unroll
            for (int s = 0; s < 2; ++s) {
                const float4* xp = (const float4*)(x + (size_t)(r0 + m) * 64 + s * 32 + quad * 8);
                float4 v0 = xp[0], v1 = xp[1];
                bf16x8 a;
                a[0] = (short)f2b(v0.x); a[1] = (short)f2b(v0.y);
                a[2] = (short)f2b(v0.z); a[3] = (short)f2b(v0.w);
                a[4] = (short)f2b(v1.x); a[5] = (short)f2b(v1.y);
                a[6] = (short)f2b(v1.z); a[7] = (short)f2b(v1.w);
#pragma unroll
                for (int t = 0; t < 4; ++t)
                    acc[t] = __builtin_amdgcn_mfma_f32_16x16x32_bf16(
                        a, bp[(s * 4 + t) * 64 + lane], acc[t], 0, 0, 0);
            }
#pragma unroll
            for (int reg = 0; reg < 4; ++reg) {
                int row = r0 + quad * 4 + reg;
#pragma unroll
                for (int t = 0; t < 4; ++t)
                    gbf[(size_t)row * 64 + t * 16 + m] = f2b(acc[t][reg]);
            }
        }
    } else {
        // ---- pack Wm1 [144x64] -> Bp (5 K-steps, K padded 160) ----
        int idx = (bid - BINB - GEMB) * 256 + tid;
        if (idx < 10240) {
            int j = idx & 7, ln = (idx >> 3) & 63, t = (idx >> 9) & 3, s = idx >> 11;
            int k = s * 32 + (ln >> 4) * 8 + j, col = t * 16 + (ln & 15);
            float v = (k < 144) ? Wm1[k * 64 + col] : 0.0f;
            Bp[idx] = f2b(v);
        }
    }
}

// K2: block b builds padded CSR for nodes [b*128, b*128+nb) in LDS, writes
// cnt + csr_pad as sequential streams.
__global__ void __launch_bounds__(256) build_csr(
        const unsigned int* __restrict__ region, const int* __restrict__ gcur,
        int* __restrict__ cnt, unsigned short* __restrict__ csr_pad, int N) {
    __shared__ unsigned short lcsr[128 * MAXDEG];   // 16 KB
    __shared__ int lcnt[128];
    int b = blockIdx.x, tid = threadIdx.x;
    if (tid < 128) lcnt[tid] = 0;
    __syncthreads();
    int ecnt = gcur[b]; if (ecnt > CAP) ecnt = CAP;
    const unsigned int* reg = region + (size_t)b * CAP;
    for (int i = tid; i < ecnt; i += 256) {
        unsigned v = reg[i];
        int dloc = (int)(v >> 16), s = (int)(v & 0xFFFFu);
        int r = atomicAdd(&lcnt[dloc], 1);          // true degree counted
        if (r < MAXDEG) lcsr[dloc * MAXDEG + r] = (unsigned short)s;
    }
    __syncthreads();
    int n0 = b << BSHIFT;
    int nb = N - n0; if (nb > 128) nb = 128;
    if (tid < nb) cnt[n0 + tid] = lcnt[tid];
    int4* gout = (int4*)(csr_pad + (size_t)n0 * MAXDEG);
    const int4* lin = (const int4*)lcsr;
    int tot = nb * 8;   // nb rows x 64 ushorts
    for (int i = tid; i < tot; i += 256) gout[i] = lin[i];
}

// K3: wave per node; dinv_s PREFETCHED 64-wide (cnt load + rsqrt hoisted
// out of the dependent inner loop), shuffled alongside the index.
__global__ void __launch_bounds__(256) gather_finalize(
        const unsigned short* __restrict__ gbf, const unsigned short* __restrict__ csr_pad,
        const int* __restrict__ cnt, const float* __restrict__ b1,
        unsigned short* __restrict__ hbf, int N) {
    int wid = blockIdx.x * 4 + (threadIdx.x >> 6);
    if (wid >= N) return;
    int lane = threadIdx.x & 63;
    int n8 = lane >> 3, c8 = lane & 7;
    int deg = cnt[wid];
    if (deg > MAXDEG) deg = MAXDEG;   // never hit: max indeg ~45
    size_t base = (size_t)wid << 6;
    const int4* gb4 = (const int4*)gbf;    // row stride = 8 int4 (128 B)
    float a[8];
#pragma unroll
    for (int k = 0; k < 8; ++k) a[k] = 0.f;

    for (int j0 = 0; j0 < deg; j0 += 64) {
        int nidx = j0 + lane;
        int sidx = 0; float dsv = 0.f;
        if (nidx < deg) {
            sidx = (int)csr_pad[base + nidx];
            dsv = rsqrtf((float)cnt[sidx] + 1.0f);   // batched, latency-hidden
        }
        int c = deg - j0; if (c > 64) c = 64;
        for (int step = 0; step * 8 < c; ++step) {
            int nn = step * 8 + n8;
            int srow = __shfl(sidx, nn, 64);
            float ds = __shfl(dsv, nn, 64);          // 0 for invalid lanes
            int4 u = make_int4(0, 0, 0, 0);
            if (nn < c) u = gb4[(size_t)srow * 8 + c8];
            a[0] += ds * __uint_as_float((unsigned)u.x << 16);
            a[1] += ds * __uint_as_float((unsigned)u.x & 0xffff0000u);
            a[2] += ds * __uint_as_float((unsigned)u.y << 16);
            a[3] += ds * __uint_as_float((unsigned)u.y & 0xffff0000u);
            a[4] += ds * __uint_as_float((unsigned)u.z << 16);
            a[5] += ds * __uint_as_float((unsigned)u.z & 0xffff0000u);
            a[6] += ds * __uint_as_float((unsigned)u.w << 16);
            a[7] += ds * __uint_as_float((unsigned)u.w & 0xffff0000u);
        }
    }
    // reduce across the 8 neighbor-groups
#pragma unroll
    for (int mask = 8; mask < 64; mask <<= 1) {
#pragma unroll
        for (int k = 0; k < 8; ++k) a[k] += __shfl_xor(a[k], mask, 64);
    }
    float dd = rsqrtf((float)deg + 1.0f);
    {   // self loop (add ONCE, after reduction — every lane has full sum)
        int4 u = gb4[(size_t)wid * 8 + c8];
        a[0] += dd * __uint_as_float((unsigned)u.x << 16);
        a[1] += dd * __uint_as_float((unsigned)u.x & 0xffff0000u);
        a[2] += dd * __uint_as_float((unsigned)u.y << 16);
        a[3] += dd * __uint_as_float((unsigned)u.y & 0xffff0000u);
        a[4] += dd * __uint_as_float((unsigned)u.z << 16);
        a[5] += dd * __uint_as_float((unsigned)u.z & 0xffff0000u);
        a[6] += dd * __uint_as_float((unsigned)u.w << 16);
        a[7] += dd * __uint_as_float((unsigned)u.w & 0xffff0000u);
    }
    if (n8 == 0) {
        const float4* bv = (const float4*)(b1 + c8 * 8);
        float4 b0 = bv[0], b14 = bv[1];
        float h0 = dd * a[0] + b0.x,  h1 = dd * a[1] + b0.y;
        float h2 = dd * a[2] + b0.z,  h3 = dd * a[3] + b0.w;
        float h4 = dd * a[4] + b14.x, h5 = dd * a[5] + b14.y;
        float h6 = dd * a[6] + b14.z, h7 = dd * a[7] + b14.w;
        h0 = h0 > 0.f ? h0 : 0.f; h1 = h1 > 0.f ? h1 : 0.f;
        h2 = h2 > 0.f ? h2 : 0.f; h3 = h3 > 0.f ? h3 : 0.f;
        h4 = h4 > 0.f ? h4 : 0.f; h5 = h5 > 0.f ? h5 : 0.f;
        h6 = h6 > 0.f ? h6 : 0.f; h7 = h7 > 0.f ? h7 : 0.f;
        int4 w;
        w.x = (int)((unsigned)f2b(h0) | ((unsigned)f2b(h1) << 16));
        w.y = (int)((unsigned)f2b(h2) | ((unsigned)f2b(h3) << 16));
        w.z = (int)((unsigned)f2b(h4) | ((unsigned)f2b(h5) << 16));
        w.w = (int)((unsigned)f2b(h6) | ((unsigned)f2b(h7) << 16));
        ((int4*)hbf)[(size_t)wid * 8 + c8] = w;
    }
}

// K4: one wave per 16 edges; K=160 (144 padded), 4 N-tiles. UNCHANGED.
__global__ void __launch_bounds__(256, 8) edge_mlp_mfma(
        const unsigned short* __restrict__ hbf, const float* __restrict__ ea,
        const int* __restrict__ src, const int* __restrict__ dst,
        const unsigned short* __restrict__ Bp,
        const float* __restrict__ bm1, const float* __restrict__ Wm2,
        const float* __restrict__ bm2, float* __restrict__ out, int E) {
    __shared__ unsigned short sB[10240];   // 20 KB
    {
        const int4* gB = (const int4*)Bp;
        int4* lB = (int4*)sB;
#pragma unroll
        for (int i = 0; i < 5; ++i)
            lB[threadIdx.x + i * 256] = gB[threadIdx.x + i * 256];
    }
    __syncthreads();
    int lane = threadIdx.x & 63;
    int wave = threadIdx.x >> 6;
    int m = lane & 15, quad = lane >> 4;
    int e0 = (blockIdx.x * 4 + wave) * 16;
    if (e0 >= E) return;
    int e = e0 + m;
    int ec = e < E ? e : E - 1;
    int si = src[ec], di = dst[ec];
    bf16x8 af[5];
    af[0] = *(const bf16x8*)(hbf + (size_t)si * 64 + quad * 8);
    af[1] = *(const bf16x8*)(hbf + (size_t)si * 64 + 32 + quad * 8);
    af[2] = *(const bf16x8*)(hbf + (size_t)di * 64 + quad * 8);
    af[3] = *(const bf16x8*)(hbf + (size_t)di * 64 + 32 + quad * 8);
    if (quad < 2) {
        const float4* ep = (const float4*)(ea + (size_t)ec * 16 + quad * 8);
        float4 v0 = ep[0], v1 = ep[1];
        af[4][0] = (short)f2b(v0.x); af[4][1] = (short)f2b(v0.y);
        af[4][2] = (short)f2b(v0.z); af[4][3] = (short)f2b(v0.w);
        af[4][4] = (short)f2b(v1.x); af[4][5] = (short)f2b(v1.y);
        af[4][6] = (short)f2b(v1.z); af[4][7] = (short)f2b(v1.w);
    } else {
#pragma unroll
        for (int j = 0; j < 8; ++j) af[4][j] = 0;
    }
    __builtin_amdgcn_sched_barrier(0);
    f32x4 acc[4];
#pragma unroll
    for (int t = 0; t < 4; ++t) acc[t] = (f32x4){0.f, 0.f, 0.f, 0.f};
    const bf16x8* bp = (const bf16x8*)sB;
#pragma unroll
    for (int s = 0; s < 5; ++s) {
#pragma unroll
        for (int t = 0; t < 4; ++t)
            acc[t] = __builtin_amdgcn_mfma_f32_16x16x32_bf16(
                af[s], bp[(s * 4 + t) * 64 + lane], acc[t], 0, 0, 0);
    }
    float w2[4], bb[4];
#pragma unroll
    for (int t = 0; t < 4; ++t) {
        int col = t * 16 + m;
        bb[t] = bm1[col];
        w2[t] = Wm2[col];
    }
    float pr[4];
#pragma unroll
    for (int r = 0; r < 4; ++r) {
        float sum = 0.0f;
#pragma unroll
        for (int t = 0; t < 4; ++t) {
            float hv = acc[t][r] + bb[t];
            sum += (hv > 0.0f ? hv : 0.0f) * w2[t];
        }
        pr[r] = sum;
    }
#pragma unroll
    for (int off = 1; off < 16; off <<= 1) {
#pragma unroll
        for (int r = 0; r < 4; ++r) pr[r] += __shfl_xor(pr[r], off, 64);
    }
    float b2 = bm2[0];
    if (m < 4) {
        int eo = e0 + quad * 4 + m;
        if (eo < E) out[eo] = 1.0f / (1.0f + __expf(-(pr[m] + b2)));
    }
}

// ================================ launcher =================================
extern "C" void kernel_launch(void* const* d_in, const int* in_sizes, int n_in,
                              void* d_out, int out_size, void* d_ws, size_t ws_size,
                              hipStream_t stream) {
    const float* x   = (const float*)d_in[0];
    const int*   src = (const int*)d_in[1];
    const int*   dst = (const int*)d_in[2];
    const float* ea  = (const float*)d_in[3];
    const float* W1  = (const float*)d_in[4];
    const float* b1  = (const float*)d_in[5];
    const float* Wm1 = (const float*)d_in[6];
    const float* bm1 = (const float*)d_in[7];
    const float* Wm2 = (const float*)d_in[8];
    const float* bm2 = (const float*)d_in[9];
    float* out = (float*)d_out;

    int N = in_sizes[0] / 64;   // 50000
    int E = in_sizes[1];        // 800000

    // ws layout (~19.5 MB; region aliases hbf — dead before K3 writes hbf):
    char* p = (char*)d_ws;
    unsigned short* gbf     = (unsigned short*)p; p += (size_t)N * 64 * 2;      // 6.4 MB
    unsigned short* hbf     = (unsigned short*)p; p += (size_t)N * 64 * 2;      // 6.4 MB
    unsigned short* csr_pad = (unsigned short*)p; p += (size_t)N * MAXDEG * 2;  // 6.4 MB
    int*            cnt     = (int*)p;            p += (size_t)N * 4;           // 0.2 MB
    int*            gcur    = (int*)p;            p += (size_t)((NBUCK * 4 + 15) / 16) * 16;
    unsigned short* Bp      = (unsigned short*)p; p += 10240 * 2;
    unsigned int*   region  = (unsigned int*)hbf;   // 4.0 MB alias (< 6.4 MB)

    hipMemsetAsync(gcur, 0, NBUCK * sizeof(int), stream);
    bin_gemm_pack<<<BINB + GEMB + BPB, 256, 0, stream>>>(
        dst, src, region, gcur, E, x, W1, gbf, Wm1, Bp, N);
    build_csr<<<NBUCK, 256, 0, stream>>>(region, gcur, cnt, csr_pad, N);
    gather_finalize<<<(N + 3) / 4, 256, 0, stream>>>(gbf, csr_pad, cnt, b1, hbf, N);
    edge_mlp_mfma<<<(E + 63) / 64, 256, 0, stream>>>(hbf, ea, src, dst, Bp,
                                                     bm1, Wm2, bm2, out, E);
}

// Round 8
// 189.045 us; speedup vs baseline: 2.6539x; 1.0089x over previous
//
#include <hip/hip_runtime.h>
#include <math.h>

// Problem constants: N=50000, E=800000, D=H=64, ED=16.
// Pipeline v9 (pre-scaled g + slice-gather; event-count driven):
//   memset gcur (391 ints)
//   K1 bin_pack: blocks [0,196) bin 4096-edge chunks (LDS sort -> coalesced
//      region runs); blocks [196,236) pack Wm1->Bp.
//   K2 build_csr: bucket per block, CSR+cnt via LDS, streamed out.
//   K3 node_gemm: gbf = bf16(rsqrt(cnt+1) * (x@W1))  [R1-R5 proven numerics]
//   K4 gather (SLICE): thread = (node, 8-col slice); 8 threads/node; NO
//      shfl, NO reduce, NO neighbor-cnt loads (g pre-scaled):
//      hbf = bf16(relu(dd*(sum g_s + g_self) + b1)), dd = rsqrt(deg+1).
//   K5 edge_mlp: unchanged (pinned 48.5us).
//
// R7 LESSON (event model, calibrated on edge_mlp: 3.2M 64B events/48.6us):
// gather was ~40us because it issued 800k random ROW events + 800k random
// CNT events. Fix = delete cnt events (pre-scale g at gemm, which now runs
// after build) + slice-gather (no cross-lane ops, 4 chains/thread).
// Cost: gemm exposed (~6us) + 1 dispatch. Predicted total ~178-184.
// DECISION RULE: if total >= 188, event model wrong -> R9 = measurement
// round (duplicate gather; dTotal = true gather duration).
//
// LESSONS ENCODED:
//  - hbf must NOT alias gbf. region aliases hbf OK (dead after K2).
//  - edge_mlp pinned ~48.5us across 6 variants. Don't tune it.
//  - R2: random-access cost is per-EVENT (~15ns/64B sector); count events,
//    not bytes. R5: cg::grid.sync is O(100us)/sync here. Never.
//  - R6: dispatch boundaries ~2-5us; fusing dispatches is NOT the lever.
//  - cnt holds TRUE degree; max indeg ~45 (seed 0); CAP=2560 = +11 sigma.

typedef __attribute__((ext_vector_type(8))) short bf16x8;
typedef __attribute__((ext_vector_type(4))) float f32x4;

#define MAXDEG 64
#define BSHIFT 7           // 128 nodes per bucket
#define BMASK 127
#define NBUCK 391          // ceil(50000/128)
#define CAP 2560           // per-bucket region capacity (mean 2046 + 11s)
#define CHUNK 4096         // edges per bin block (16/thread)
#define BINB 196           // ceil(800000/4096)
#define BPB 40             // Bp pack blocks = 10240/256

__device__ __forceinline__ unsigned short f2b(float f) {
    unsigned u = __float_as_uint(f);
    unsigned r = (u + 0x7FFFu + ((u >> 16) & 1u)) >> 16;   // RNE
    return (unsigned short)r;
}

// K1: bin role + Bp-pack role (independent of everything downstream).
__global__ void __launch_bounds__(256) bin_pack(
        const int* __restrict__ dst, const int* __restrict__ src,
        unsigned int* __restrict__ region, int* __restrict__ gcur, int E,
        const float* __restrict__ Wm1, unsigned short* __restrict__ Bp) {
    __shared__ __align__(16) char smem[32768];
    const int bid = blockIdx.x, tid = threadIdx.x;

    if (bid < BINB) {
        // ---- bin role: histogram -> rank -> scan -> LDS sort -> run writes
        int* lc = (int*)smem;                         // [512] counts
        int* s0 = lc + 512;                           // [512] scan ping
        int* s1 = s0 + 512;                           // [512] scan pong
        int* gb = s1 + 512;                           // [512] global bases
        unsigned* lval = (unsigned*)(gb + 512);       // [4096] 16KB
        unsigned short* lbuk = (unsigned short*)(lval + 4096);  // [4096] 8KB

        for (int i = tid; i < 512; i += 256) lc[i] = 0;
        __syncthreads();

        // count + rank (16 edges/thread via 4x int4, coalesced)
        unsigned kb[16], kv[16];
#pragma unroll
        for (int j = 0; j < 4; ++j) {
            int i4 = bid * 1024 + j * 256 + tid;      // int4 index
            bool ok = (i4 * 4 < E);                   // E % 4 == 0
            int4 d4 = make_int4(0, 0, 0, 0), s4 = make_int4(0, 0, 0, 0);
            if (ok) { d4 = ((const int4*)dst)[i4]; s4 = ((const int4*)src)[i4]; }
            int dd[4] = {d4.x, d4.y, d4.z, d4.w};
            int ss[4] = {s4.x, s4.y, s4.z, s4.w};
#pragma unroll
            for (int k = 0; k < 4; ++k) {
                int idx = j * 4 + k;
                kb[idx] = 0xFFFFFFFFu;
                if (ok) {
                    int b = dd[k] >> BSHIFT;
                    int r = atomicAdd(&lc[b], 1);     // LDS atomic: local rank
                    kb[idx] = ((unsigned)b << 12) | (unsigned)r;   // b<512, r<4096
                    kv[idx] = ((unsigned)(dd[k] & BMASK) << 16) | (unsigned)ss[k];
                }
            }
        }
        __syncthreads();

        // inclusive scan (Hillis-Steele, 512 wide) -> exclusive bases in lb
        for (int i = tid; i < 512; i += 256) s0[i] = lc[i];
        __syncthreads();
        int* pin = s0; int* pout = s1;
        for (int off = 1; off < 512; off <<= 1) {
            for (int i = tid; i < 512; i += 256) {
                int v = pin[i];
                if (i >= off) v += pin[i - off];
                pout[i] = v;
            }
            __syncthreads();
            int* t = pin; pin = pout; pout = t;
        }
        int* lb = pout;   // free buffer
        for (int i = tid; i < 512; i += 256) lb[i] = pin[i] - lc[i];
        // global base reservation: ONE atomic per non-empty bucket
        for (int i = tid; i < NBUCK; i += 256) {
            int c = lc[i];
            gb[i] = c ? atomicAdd(&gcur[i], c) : 0;
        }
        __syncthreads();

        // scatter into LDS bucket-sorted order
#pragma unroll
        for (int idx = 0; idx < 16; ++idx) {
            if (kb[idx] != 0xFFFFFFFFu) {
                int b = (int)(kb[idx] >> 12), r = (int)(kb[idx] & 4095u);
                int pos = lb[b] + r;
                lval[pos] = kv[idx];
                lbuk[pos] = (unsigned short)b;
            }
        }
        __syncthreads();

        // write out: consecutive i within a bucket -> consecutive addresses
        int ne = E - bid * CHUNK; if (ne > CHUNK) ne = CHUNK;
        for (int i = tid; i < ne; i += 256) {
            int b = lbuk[i];
            int idx = gb[b] + (i - lb[b]);
            if (idx < CAP) region[(size_t)b * CAP + idx] = lval[i];
        }
    } else {
        // ---- pack Wm1 [144x64] -> Bp (5 K-steps, K padded 160) ----
        int idx = (bid - BINB) * 256 + tid;
        if (idx < 10240) {
            int j = idx & 7, ln = (idx >> 3) & 63, t = (idx >> 9) & 3, s = idx >> 11;
            int k = s * 32 + (ln >> 4) * 8 + j, col = t * 16 + (ln & 15);
            float v = (k < 144) ? Wm1[k * 64 + col] : 0.0f;
            Bp[idx] = f2b(v);
        }
    }
}

// K2: block b builds padded CSR for nodes [b*128, b*128+nb) in LDS, writes
// cnt + csr_pad as sequential streams.
__global__ void __launch_bounds__(256) build_csr(
        const unsigned int* __restrict__ region, const int* __restrict__ gcur,
        int* __restrict__ cnt, unsigned short* __restrict__ csr_pad, int N) {
    __shared__ unsigned short lcsr[128 * MAXDEG];   // 16 KB
    __shared__ int lcnt[128];
    int b = blockIdx.x, tid = threadIdx.x;
    if (tid < 128) lcnt[tid] = 0;
    __syncthreads();
    int ecnt = gcur[b]; if (ecnt > CAP) ecnt = CAP;
    const unsigned int* reg = region + (size_t)b * CAP;
    for (int i = tid; i < ecnt; i += 256) {
        unsigned v = reg[i];
        int dloc = (int)(v >> 16), s = (int)(v & 0xFFFFu);
        int r = atomicAdd(&lcnt[dloc], 1);          // true degree counted
        if (r < MAXDEG) lcsr[dloc * MAXDEG + r] = (unsigned short)s;
    }
    __syncthreads();
    int n0 = b << BSHIFT;
    int nb = N - n0; if (nb > 128) nb = 128;
    if (tid < nb) cnt[n0 + tid] = lcnt[tid];
    int4* gout = (int4*)(csr_pad + (size_t)n0 * MAXDEG);
    const int4* lin = (const int4*)lcsr;
    int tot = nb * 8;   // nb rows x 64 ushorts
    for (int i = tid; i < tot; i += 256) gout[i] = lin[i];
}

// K3: node GEMM (wave per 16 rows), self-packed W1, PRE-SCALED output:
// gbf = bf16(rsqrt(cnt+1) * (x@W1))   [R1-R5 proven numeric path]
__global__ void __launch_bounds__(256) node_gemm_mfma(
        const float* __restrict__ x, const float* __restrict__ W1,
        const int* __restrict__ cnt, unsigned short* __restrict__ gbf, int NWT) {
    __shared__ unsigned short sB[4096];   // 8 KB
    for (int i = threadIdx.x; i < 4096; i += 256) {
        int j = i & 7, ln = (i >> 3) & 63, t = (i >> 9) & 3, s = i >> 11;
        int k = s * 32 + (ln >> 4) * 8 + j, col = t * 16 + (ln & 15);
        sB[i] = f2b(W1[k * 64 + col]);
    }
    __syncthreads();
    int wid = blockIdx.x * 4 + (threadIdx.x >> 6);
    if (wid >= NWT) return;
    int lane = threadIdx.x & 63, m = lane & 15, quad = lane >> 4;
    int r0 = wid * 16;
    f32x4 acc[4];
#pragma unroll
    for (int t = 0; t < 4; ++t) acc[t] = (f32x4){0.f, 0.f, 0.f, 0.f};
    const bf16x8* bp = (const bf16x8*)sB;
#pragma unroll
    for (int s = 0; s < 2; ++s) {
        const float4* xp = (const float4*)(x + (size_t)(r0 + m) * 64 + s * 32 + quad * 8);
        float4 v0 = xp[0], v1 = xp[1];
        bf16x8 a;
        a[0] = (short)f2b(v0.x); a[1] = (short)f2b(v0.y);
        a[2] = (short)f2b(v0.z); a[3] = (short)f2b(v0.w);
        a[4] = (short)f2b(v1.x); a[5] = (short)f2b(v1.y);
        a[6] = (short)f2b(v1.z); a[7] = (short)f2b(v1.w);
#pragma unroll
        for (int t = 0; t < 4; ++t)
            acc[t] = __builtin_amdgcn_mfma_f32_16x16x32_bf16(
                a, bp[(s * 4 + t) * 64 + lane], acc[t], 0, 0, 0);
    }
#pragma unroll
    for (int reg = 0; reg < 4; ++reg) {
        int row = r0 + quad * 4 + reg;
        float di = rsqrtf((float)cnt[row] + 1.0f);
#pragma unroll
        for (int t = 0; t < 4; ++t)
            gbf[(size_t)row * 64 + t * 16 + m] = f2b(acc[t][reg] * di);
    }
}

#define ACC8(U) \
    a0 += __uint_as_float((unsigned)(U).x << 16); \
    a1 += __uint_as_float((unsigned)(U).x & 0xffff0000u); \
    a2 += __uint_as_float((unsigned)(U).y << 16); \
    a3 += __uint_as_float((unsigned)(U).y & 0xffff0000u); \
    a4 += __uint_as_float((unsigned)(U).z << 16); \
    a5 += __uint_as_float((unsigned)(U).z & 0xffff0000u); \
    a6 += __uint_as_float((unsigned)(U).w << 16); \
    a7 += __uint_as_float((unsigned)(U).w & 0xffff0000u);

// K4: SLICE gather — thread = (node, 8-col slice), 8 threads/node, 32
// nodes/block. No shfl, no reduce, no neighbor-cnt loads. Unroll-4 gives
// 4 independent csr->row chains per thread. Stores fully coalesced.
__global__ void __launch_bounds__(256) gather_finalize(
        const unsigned short* __restrict__ gbf, const unsigned short* __restrict__ csr_pad,
        const int* __restrict__ cnt, const float* __restrict__ b1,
        unsigned short* __restrict__ hbf, int N) {
    int t = blockIdx.x * 256 + threadIdx.x;
    int node = t >> 3;
    if (node >= N) return;
    int c8 = t & 7;
    int deg = cnt[node];
    if (deg > MAXDEG) deg = MAXDEG;   // never hit: max indeg ~45
    size_t base = (size_t)node << 6;
    const int4* gb4 = (const int4*)gbf;    // row stride = 8 int4 (128 B)
    float a0 = 0.f, a1 = 0.f, a2 = 0.f, a3 = 0.f,
          a4 = 0.f, a5 = 0.f, a6 = 0.f, a7 = 0.f;
    int j = 0;
    for (; j + 4 <= deg; j += 4) {
        int s0 = (int)csr_pad[base + j];
        int s1 = (int)csr_pad[base + j + 1];
        int s2 = (int)csr_pad[base + j + 2];
        int s3 = (int)csr_pad[base + j + 3];
        int4 u0 = gb4[(size_t)s0 * 8 + c8];
        int4 u1 = gb4[(size_t)s1 * 8 + c8];
        int4 u2 = gb4[(size_t)s2 * 8 + c8];
        int4 u3 = gb4[(size_t)s3 * 8 + c8];
        ACC8(u0) ACC8(u1) ACC8(u2) ACC8(u3)
    }
    for (; j < deg; ++j) {
        int s0 = (int)csr_pad[base + j];
        int4 u0 = gb4[(size_t)s0 * 8 + c8];
        ACC8(u0)
    }
    {   // self loop (g pre-scaled: agg = dd*(sum g_s + g_self))
        int4 u = gb4[(size_t)node * 8 + c8];
        ACC8(u)
    }
    float dd = rsqrtf((float)deg + 1.0f);
    const float4* bv = (const float4*)(b1 + c8 * 8);
    float4 b0 = bv[0], b14 = bv[1];
    float h0 = dd * a0 + b0.x,  h1 = dd * a1 + b0.y;
    float h2 = dd * a2 + b0.z,  h3 = dd * a3 + b0.w;
    float h4 = dd * a4 + b14.x, h5 = dd * a5 + b14.y;
    float h6 = dd * a6 + b14.z, h7 = dd * a7 + b14.w;
    h0 = h0 > 0.f ? h0 : 0.f; h1 = h1 > 0.f ? h1 : 0.f;
    h2 = h2 > 0.f ? h2 : 0.f; h3 = h3 > 0.f ? h3 : 0.f;
    h4 = h4 > 0.f ? h4 : 0.f; h5 = h5 > 0.f ? h5 : 0.f;
    h6 = h6 > 0.f ? h6 : 0.f; h7 = h7 > 0.f ? h7 : 0.f;
    int4 w;
    w.x = (int)((unsigned)f2b(h0) | ((unsigned)f2b(h1) << 16));
    w.y = (int)((unsigned)f2b(h2) | ((unsigned)f2b(h3) << 16));
    w.z = (int)((unsigned)f2b(h4) | ((unsigned)f2b(h5) << 16));
    w.w = (int)((unsigned)f2b(h6) | ((unsigned)f2b(h7) << 16));
    ((int4*)hbf)[(size_t)node * 8 + c8] = w;
}

// K5: one wave per 16 edges; K=160 (144 padded), 4 N-tiles. UNCHANGED.
__global__ void __launch_bounds__(256, 8) edge_mlp_mfma(
        const unsigned short* __restrict__ hbf, const float* __restrict__ ea,
        const int* __restrict__ src, const int* __restrict__ dst,
        const unsigned short* __restrict__ Bp,
        const float* __restrict__ bm1, const float* __restrict__ Wm2,
        const float* __restrict__ bm2, float* __restrict__ out, int E) {
    __shared__ unsigned short sB[10240];   // 20 KB
    {
        const int4* gB = (const int4*)Bp;
        int4* lB = (int4*)sB;
#pragma unroll
        for (int i = 0; i < 5; ++i)
            lB[threadIdx.x + i * 256] = gB[threadIdx.x + i * 256];
    }
    __syncthreads();
    int lane = threadIdx.x & 63;
    int wave = threadIdx.x >> 6;
    int m = lane & 15, quad = lane >> 4;
    int e0 = (blockIdx.x * 4 + wave) * 16;
    if (e0 >= E) return;
    int e = e0 + m;
    int ec = e < E ? e : E - 1;
    int si = src[ec], di = dst[ec];
    bf16x8 af[5];
    af[0] = *(const bf16x8*)(hbf + (size_t)si * 64 + quad * 8);
    af[1] = *(const bf16x8*)(hbf + (size_t)si * 64 + 32 + quad * 8);
    af[2] = *(const bf16x8*)(hbf + (size_t)di * 64 + quad * 8);
    af[3] = *(const bf16x8*)(hbf + (size_t)di * 64 + 32 + quad * 8);
    if (quad < 2) {
        const float4* ep = (const float4*)(ea + (size_t)ec * 16 + quad * 8);
        float4 v0 = ep[0], v1 = ep[1];
        af[4][0] = (short)f2b(v0.x); af[4][1] = (short)f2b(v0.y);
        af[4][2] = (short)f2b(v0.z); af[4][3] = (short)f2b(v0.w);
        af[4][4] = (short)f2b(v1.x); af[4][5] = (short)f2b(v1.y);
        af[4][6] = (short)f2b(v1.z); af[4][7] = (short)f2b(v1.w);
    } else {
#pragma unroll
        for (int j = 0; j < 8; ++j) af[4][j] = 0;
    }
    __builtin_amdgcn_sched_barrier(0);
    f32x4 acc[4];
#pragma unroll
    for (int t = 0; t < 4; ++t) acc[t] = (f32x4){0.f, 0.f, 0.f, 0.f};
    const bf16x8* bp = (const bf16x8*)sB;
#pragma unroll
    for (int s = 0; s < 5; ++s) {
#pragma unroll
        for (int t = 0; t < 4; ++t)
            acc[t] = __builtin_amdgcn_mfma_f32_16x16x32_bf16(
                af[s], bp[(s * 4 + t) * 64 + lane], acc[t], 0, 0, 0);
    }
    float w2[4], bb[4];
#pragma unroll
    for (int t = 0; t < 4; ++t) {
        int col = t * 16 + m;
        bb[t] = bm1[col];
        w2[t] = Wm2[col];
    }
    float pr[4];
#pragma unroll
    for (int r = 0; r < 4; ++r) {
        float sum = 0.0f;
#pragma unroll
        for (int t = 0; t < 4; ++t) {
            float hv = acc[t][r] + bb[t];
            sum += (hv > 0.0f ? hv : 0.0f) * w2[t];
        }
        pr[r] = sum;
    }
#pragma unroll
    for (int off = 1; off < 16; off <<= 1) {
#pragma unroll
        for (int r = 0; r < 4; ++r) pr[r] += __shfl_xor(pr[r], off, 64);
    }
    float b2 = bm2[0];
    if (m < 4) {
        int eo = e0 + quad * 4 + m;
        if (eo < E) out[eo] = 1.0f / (1.0f + __expf(-(pr[m] + b2)));
    }
}

// ================================ launcher =================================
extern "C" void kernel_launch(void* const* d_in, const int* in_sizes, int n_in,
                              void* d_out, int out_size, void* d_ws, size_t ws_size,
                              hipStream_t stream) {
    const float* x   = (const float*)d_in[0];
    const int*   src = (const int*)d_in[1];
    const int*   dst = (const int*)d_in[2];
    const float* ea  = (const float*)d_in[3];
    const float* W1  = (const float*)d_in[4];
    const float* b1  = (const float*)d_in[5];
    const float* Wm1 = (const float*)d_in[6];
    const float* bm1 = (const float*)d_in[7];
    const float* Wm2 = (const float*)d_in[8];
    const float* bm2 = (const float*)d_in[9];
    float* out = (float*)d_out;

    int N = in_sizes[0] / 64;   // 50000
    int E = in_sizes[1];        // 800000
    int NWT = N / 16;           // 3125

    // ws layout (~19.5 MB; region aliases hbf — dead before K4 writes hbf):
    char* p = (char*)d_ws;
    unsigned short* gbf     = (unsigned short*)p; p += (size_t)N * 64 * 2;      // 6.4 MB
    unsigned short* hbf     = (unsigned short*)p; p += (size_t)N * 64 * 2;      // 6.4 MB
    unsigned short* csr_pad = (unsigned short*)p; p += (size_t)N * MAXDEG * 2;  // 6.4 MB
    int*            cnt     = (int*)p;            p += (size_t)N * 4;           // 0.2 MB
    int*            gcur    = (int*)p;            p += (size_t)((NBUCK * 4 + 15) / 16) * 16;
    unsigned short* Bp      = (unsigned short*)p; p += 10240 * 2;
    unsigned int*   region  = (unsigned int*)hbf;   // 4.0 MB alias (< 6.4 MB)

    hipMemsetAsync(gcur, 0, NBUCK * sizeof(int), stream);
    bin_pack<<<BINB + BPB, 256, 0, stream>>>(dst, src, region, gcur, E, Wm1, Bp);
    build_csr<<<NBUCK, 256, 0, stream>>>(region, gcur, cnt, csr_pad, N);
    node_gemm_mfma<<<(NWT + 3) / 4, 256, 0, stream>>>(x, W1, cnt, gbf, NWT);
    gather_finalize<<<(N * 8 + 255) / 256, 256, 0, stream>>>(gbf, csr_pad, cnt, b1, hbf, N);
    edge_mlp_mfma<<<(E + 63) / 64, 256, 0, stream>>>(hbf, ea, src, dst, Bp,
                                                     bm1, Wm2, bm2, out, E);
}